// Round 7
// baseline (665.672 us; speedup 1.0000x reference)
//
#include <hip/hip_runtime.h>
#include <hip/hip_bf16.h>
#include <math.h>

typedef unsigned short u16;
typedef __attribute__((ext_vector_type(8))) short frag8;
typedef __attribute__((ext_vector_type(4))) float f32x4;
typedef __attribute__((ext_vector_type(8))) unsigned short us8;
typedef __attribute__((ext_vector_type(4))) unsigned short us4;

#define B_ 8
#define C_ 512
#define D_ 512
#define N_ 4096

__device__ __forceinline__ float b2f(u16 u){ union { unsigned int i; float f; } v; v.i = ((unsigned int)u) << 16; return v.f; }
__device__ __forceinline__ u16 f2b(float f){ union { float f; unsigned int i; } v; v.f = f; unsigned int x = v.i; return (u16)((x + 0x7fffu + ((x >> 16) & 1u)) >> 16); }
__device__ __forceinline__ float sigm(float x){ return 1.0f / (1.0f + __expf(-x)); }

// async global->LDS, 16B per lane; LDS dest is wave-uniform base + lane*16
__device__ __forceinline__ void gl2l(const u16* g, u16* l){
    __builtin_amdgcn_global_load_lds((const __attribute__((address_space(1))) void*)g,
                                     (__attribute__((address_space(3))) void*)l, 16, 0, 0);
}

// load 8 consecutive elements as bf16 from fp32 (fl=1) or bf16 (fl=0) source
__device__ __forceinline__ us8 load_x8(const void* __restrict__ x, int fl, size_t off){
    if (fl){
        const float* p = (const float*)x + off;
        f32x4 a = *(const f32x4*)p;
        f32x4 b = *(const f32x4*)(p + 4);
        us8 o;
        #pragma unroll
        for (int j = 0; j < 4; ++j){ o[j] = f2b(a[j]); o[4 + j] = f2b(b[j]); }
        return o;
    }
    return *(const us8*)((const u16*)x + off);
}

// ---------------- dtype detect: bf16 vs fp32 ----------------
__global__ __launch_bounds__(256) void k_detect(const unsigned int* __restrict__ x, int* __restrict__ flag){
    int tid = threadIdx.x;
    unsigned int w = x[tid];
    int e = (int)((w >> 7) & 0xFFu);
    int in = (e >= 100 && e <= 140) ? 1 : 0;
    __shared__ int sm[4];
    for (int off = 32; off > 0; off >>= 1) in += __shfl_down(in, off);
    if ((tid & 63) == 0) sm[tid >> 6] = in;
    __syncthreads();
    if (tid == 0) *flag = ((sm[0] + sm[1] + sm[2] + sm[3]) < 128) ? 1 : 0;  // 1 = fp32
}

__global__ __launch_bounds__(256) void k_convert(const void* __restrict__ src, u16* __restrict__ dst,
                                                 int n, const int* __restrict__ flag){
    int i = (blockIdx.x * 256 + threadIdx.x) * 8;
    if (i >= n) return;
    *(us8*)(dst + i) = load_x8(src, *flag, (size_t)i);
}

// ---------------- xT[b][n][c] = x[b][c][n] as bf16 (64x64 LDS tile transpose) ----------------
__global__ __launch_bounds__(256) void k_xpose(const void* __restrict__ x, const int* __restrict__ flag,
                                               u16* __restrict__ xT){
    __shared__ __attribute__((aligned(16))) u16 T[64][72];
    int rt = blockIdx.y;              // row tile over b*C
    int b = rt >> 3, c0 = (rt & 7) * 64;
    int n0 = blockIdx.x * 64;
    int tid = threadIdx.x, fl = *flag;
    int row = tid >> 2, cg = (tid & 3) * 16;
    size_t base = ((size_t)b * C_ + c0 + row) * N_ + n0 + cg;
    us8 v0 = load_x8(x, fl, base);
    us8 v1 = load_x8(x, fl, base + 8);
    #pragma unroll
    for (int j = 0; j < 8; ++j){ T[cg + j][row] = v0[j]; T[cg + 8 + j][row] = v1[j]; }
    __syncthreads();
    int col = tid >> 2, rg = (tid & 3) * 16;
    us8 o0 = *(const us8*)&T[col][rg];
    us8 o1 = *(const us8*)&T[col][rg + 8];
    u16* dst = xT + ((size_t)b * N_ + n0 + col) * C_ + c0 + rg;
    *(us8*)dst = o0;
    *(us8*)(dst + 8) = o1;
}

// ---------------- mx[k] = mean over (b,n) of x ----------------
__global__ __launch_bounds__(256) void k_xmean(const void* __restrict__ x, const int* __restrict__ flag,
                                               float* __restrict__ mx){
    int k = blockIdx.x, tid = threadIdx.x, fl = *flag;
    float sum = 0.f;
    for (int b = 0; b < B_; ++b){
        size_t base = ((size_t)b * C_ + k) * N_;
        for (int i = tid * 8; i < N_; i += 2048){
            us8 v = load_x8(x, fl, base + i);
            #pragma unroll
            for (int j = 0; j < 8; ++j) sum += b2f(v[j]);
        }
    }
    __shared__ float sm[4];
    for (int off = 32; off > 0; off >>= 1) sum += __shfl_down(sum, off);
    if ((tid & 63) == 0) sm[tid >> 6] = sum;
    __syncthreads();
    if (tid == 0) mx[k] = (sm[0] + sm[1] + sm[2] + sm[3]) * (1.0f / 32768.0f);
}

// ---------------- Gram split-K (m97+dbuf): Gf[k][k'] += partial over (b, n-chunk) ----------------
__global__ __launch_bounds__(256) void k_gram_split(const u16* __restrict__ xc, float* __restrict__ Gf){
    __shared__ __attribute__((aligned(16))) u16 As[2][128 * 32];
    __shared__ __attribute__((aligned(16))) u16 Bs[2][128 * 32];
    int k0 = blockIdx.y * 128, kp0 = blockIdx.x * 128;
    int s = blockIdx.z;
    int b = s >> 2, nbase = (s & 3) * 1024;
    int tid = threadIdx.x, w = tid >> 6, l = tid & 63, lr = l & 15, q = l >> 4;
    int wr = w & 1, wcn = w >> 1;
    int srow = l >> 2, scol = (l & 3) * 8;
    const u16* ap = xc + ((size_t)b * C_ + k0 + w * 16 + srow) * N_ + nbase + scol;
    const u16* bp = xc + ((size_t)b * C_ + kp0 + w * 16 + srow) * N_ + nbase + scol;
    f32x4 acc[4][4] = {};
    // prologue: stage tile 0 into buf 0
    gl2l(ap, As[0] + w * 512);
    gl2l(ap + (size_t)64 * N_, As[0] + w * 512 + 2048);
    gl2l(bp, Bs[0] + w * 512);
    gl2l(bp + (size_t)64 * N_, Bs[0] + w * 512 + 2048);
    __syncthreads();
    int cur = 0;
    for (int t = 0; t < 32; ++t){
        if (t < 31){
            int kn = (t + 1) * 32;
            u16* la = As[cur ^ 1] + w * 512;
            u16* lb = Bs[cur ^ 1] + w * 512;
            gl2l(ap + kn, la);
            gl2l(ap + kn + (size_t)64 * N_, la + 2048);
            gl2l(bp + kn, lb);
            gl2l(bp + kn + (size_t)64 * N_, lb + 2048);
        }
        frag8 af[4], bf[4];
        #pragma unroll
        for (int i = 0; i < 4; ++i){
            af[i] = *(const frag8*)&As[cur][(wr * 64 + i * 16 + lr) * 32 + q * 8];
            bf[i] = *(const frag8*)&Bs[cur][(wcn * 64 + i * 16 + lr) * 32 + q * 8];
        }
        #pragma unroll
        for (int mi = 0; mi < 4; ++mi)
            #pragma unroll
            for (int ni = 0; ni < 4; ++ni)
                acc[mi][ni] = __builtin_amdgcn_mfma_f32_16x16x32_bf16(af[mi], bf[ni], acc[mi][ni], 0, 0, 0);
        __syncthreads();
        cur ^= 1;
    }
    #pragma unroll
    for (int mi = 0; mi < 4; ++mi)
        #pragma unroll
        for (int ni = 0; ni < 4; ++ni)
            #pragma unroll
            for (int r = 0; r < 4; ++r)
                atomicAdd(&Gf[(size_t)(k0 + wr * 64 + mi * 16 + q * 4 + r) * C_ + kp0 + wcn * 64 + ni * 16 + lr],
                          acc[mi][ni][r]);
}

// Gf fp32 -> Gb bf16 with 1/32768 scale
__global__ __launch_bounds__(256) void k_gram_fin(const float* __restrict__ Gf, u16* __restrict__ Gb){
    int i = blockIdx.x * 256 + threadIdx.x;
    Gb[i] = f2b(Gf[i] * (1.0f / 32768.0f));
}

// ---------------- T = W * G (fp32 out), G symmetric ----------------
__global__ __launch_bounds__(256) void k_wg(const u16* __restrict__ wc, const u16* __restrict__ Gb, float* __restrict__ T){
    __shared__ __attribute__((aligned(16))) u16 As[64][40];
    __shared__ __attribute__((aligned(16))) u16 Bs[64][40];
    int o0 = blockIdx.y * 64, kp0 = blockIdx.x * 64;
    int tid = threadIdx.x, row = tid >> 2, cg = (tid & 3) * 8;
    const u16* ap = wc + (size_t)(o0 + row) * C_ + cg;
    const u16* bp = Gb + (size_t)(kp0 + row) * C_ + cg;
    int w = tid >> 6, l = tid & 63, lr = l & 15, q = l >> 4;
    f32x4 acc[4] = {};
    for (int k0 = 0; k0 < 512; k0 += 32){
        *(us8*)&As[row][cg] = *(const us8*)(ap + k0);
        *(us8*)&Bs[row][cg] = *(const us8*)(bp + k0);
        __syncthreads();
        frag8 af = *(const frag8*)&As[w * 16 + lr][q * 8];
        #pragma unroll
        for (int t4 = 0; t4 < 4; ++t4){
            frag8 bfv = *(const frag8*)&Bs[t4 * 16 + lr][q * 8];
            acc[t4] = __builtin_amdgcn_mfma_f32_16x16x32_bf16(af, bfv, acc[t4], 0, 0, 0);
        }
        __syncthreads();
    }
    #pragma unroll
    for (int t4 = 0; t4 < 4; ++t4)
        #pragma unroll
        for (int r = 0; r < 4; ++r)
            T[(size_t)(o0 + w * 16 + q * 4 + r) * C_ + kp0 + t4 * 16 + lr] = acc[t4][r];
}

// ---------------- BN1 finalize ----------------
__global__ __launch_bounds__(256) void k_bn1fin(const float* __restrict__ T, const u16* __restrict__ wc,
                                                const float* __restrict__ mx, const u16* __restrict__ g1,
                                                const u16* __restrict__ b1, float* __restrict__ s1,
                                                float* __restrict__ t1){
    int o = blockIdx.x, tid = threadIdx.x;
    float e2 = 0.f, mn = 0.f;
    for (int k = tid; k < 512; k += 256){
        float wv = b2f(wc[(size_t)o * C_ + k]);
        e2 += T[(size_t)o * C_ + k] * wv;
        mn += wv * mx[k];
    }
    __shared__ float sm[8];
    for (int off = 32; off > 0; off >>= 1){ e2 += __shfl_down(e2, off); mn += __shfl_down(mn, off); }
    int w = tid >> 6;
    if ((tid & 63) == 0){ sm[w] = e2; sm[4 + w] = mn; }
    __syncthreads();
    if (tid == 0){
        float E2 = sm[0] + sm[1] + sm[2] + sm[3];
        float M  = sm[4] + sm[5] + sm[6] + sm[7];
        float var = E2 - M * M;
        float inv = rsqrtf(var + 1e-5f);
        float sc = b2f(g1[o]) * inv;
        s1[o] = sc;
        t1[o] = b2f(b1[o]) - M * sc;
    }
}

// ---------------- GEMM1 (batched), fused BN + activation — m97 + double-buffer prefetch ----------------
template<int PHASE>
__global__ __launch_bounds__(256) void k_gemm_act(const u16* __restrict__ wc, const u16* __restrict__ xT,
                                                  const float* __restrict__ s1, const float* __restrict__ t1,
                                                  u16* __restrict__ dst){
    __shared__ __attribute__((aligned(16))) u16 As[2][128 * 32];
    __shared__ __attribute__((aligned(16))) u16 Bs[2][128 * 32];
    int b = blockIdx.z, n0 = blockIdx.x * 128, my = blockIdx.y;
    int c0 = (PHASE == 1) ? (512 + my * 128) : ((my < 4) ? my * 128 : 1536 + (my - 4) * 128);
    int tid = threadIdx.x, w = tid >> 6, l = tid & 63, lr = l & 15, q = l >> 4;
    int wr = w & 1, wcn = w >> 1;              // wave quadrant: rows wr*64, cols wcn*64
    int srow = l >> 2, scol = (l & 3) * 8;     // staging lane map (16 rows x 32 cols per wave-chunk)
    const u16* ap = wc + (size_t)(c0 + w * 16 + srow) * C_ + scol;
    const u16* bp = xT + ((size_t)b * N_ + n0 + w * 16 + srow) * C_ + scol;
    f32x4 acc[4][4] = {};
    gl2l(ap, As[0] + w * 512);
    gl2l(ap + (size_t)64 * C_, As[0] + w * 512 + 2048);
    gl2l(bp, Bs[0] + w * 512);
    gl2l(bp + (size_t)64 * C_, Bs[0] + w * 512 + 2048);
    __syncthreads();
    int cur = 0;
    for (int t = 0; t < 16; ++t){
        if (t < 15){
            int kn = (t + 1) * 32;
            u16* la = As[cur ^ 1] + w * 512;
            u16* lb = Bs[cur ^ 1] + w * 512;
            gl2l(ap + kn, la);
            gl2l(ap + kn + (size_t)64 * C_, la + 2048);
            gl2l(bp + kn, lb);
            gl2l(bp + kn + (size_t)64 * C_, lb + 2048);
        }
        frag8 af[4], bf[4];
        #pragma unroll
        for (int i = 0; i < 4; ++i){
            af[i] = *(const frag8*)&As[cur][(wr * 64 + i * 16 + lr) * 32 + q * 8];
            bf[i] = *(const frag8*)&Bs[cur][(wcn * 64 + i * 16 + lr) * 32 + q * 8];
        }
        #pragma unroll
        for (int mi = 0; mi < 4; ++mi)
            #pragma unroll
            for (int ni = 0; ni < 4; ++ni)
                acc[mi][ni] = __builtin_amdgcn_mfma_f32_16x16x32_bf16(af[mi], bf[ni], acc[mi][ni], 0, 0, 0);
        __syncthreads();
        cur ^= 1;
    }
    #pragma unroll
    for (int mi = 0; mi < 4; ++mi){
        int cb = c0 + wr * 64 + mi * 16 + q * 4;
        #pragma unroll
        for (int ni = 0; ni < 4; ++ni){
            int n = n0 + wcn * 64 + ni * 16 + lr;
            us4 o4;
            #pragma unroll
            for (int r = 0; r < 4; ++r){
                int c = cb + r;
                float ybn = acc[mi][ni][r] * s1[c] + t1[c];
                float ov = (c < 1024) ? sigm(ybn) : ((c < 1536) ? ybn : ybn * sigm(ybn));
                if (PHASE == 1)
                    dst[((size_t)b * 1024 + (c - 512)) * N_ + n] = f2b(ov);
                else
                    o4[r] = f2b(ov);
            }
            if (PHASE == 2){
                int col = (cb < 512) ? cb : (cb - 1024);
                *(us4*)(dst + ((size_t)b * N_ + n) * 1024 + col) = o4;
            }
        }
    }
}

// ---------------- vk[b][d][e] = (1/N) sum_n v[d][n] * k[e][n] — m97 + double-buffer ----------------
__global__ __launch_bounds__(256) void k_vk(const u16* __restrict__ kv, u16* __restrict__ vk){
    __shared__ __attribute__((aligned(16))) u16 As[2][64 * 32];    // v-tile
    __shared__ __attribute__((aligned(16))) u16 Bs[2][128 * 32];   // k-tile
    int b = blockIdx.z, d0 = blockIdx.y * 64, e0 = blockIdx.x * 128;
    int tid = threadIdx.x, w = tid >> 6, l = tid & 63, lr = l & 15, q = l >> 4;
    int wr = w & 1, wcn = w >> 1;               // quadrant: d rows wr*32, e cols wcn*64
    int srow = l >> 2, scol = (l & 3) * 8;
    const u16* ap = kv + ((size_t)b * 1024 + 512 + d0 + w * 16 + srow) * N_ + scol;
    const u16* bp = kv + ((size_t)b * 1024 + e0 + w * 32 + srow) * N_ + scol;
    f32x4 acc[2][4] = {};
    gl2l(ap, As[0] + w * 512);
    gl2l(bp, Bs[0] + w * 1024);
    gl2l(bp + (size_t)16 * N_, Bs[0] + w * 1024 + 512);
    __syncthreads();
    int cur = 0;
    for (int t = 0; t < 128; ++t){
        if (t < 127){
            int nn0 = (t + 1) * 32;
            gl2l(ap + nn0, As[cur ^ 1] + w * 512);
            gl2l(bp + nn0, Bs[cur ^ 1] + w * 1024);
            gl2l(bp + nn0 + (size_t)16 * N_, Bs[cur ^ 1] + w * 1024 + 512);
        }
        frag8 af[2], bf[4];
        #pragma unroll
        for (int i = 0; i < 2; ++i)
            af[i] = *(const frag8*)&As[cur][(wr * 32 + i * 16 + lr) * 32 + q * 8];
        #pragma unroll
        for (int i = 0; i < 4; ++i)
            bf[i] = *(const frag8*)&Bs[cur][(wcn * 64 + i * 16 + lr) * 32 + q * 8];
        #pragma unroll
        for (int mi = 0; mi < 2; ++mi)
            #pragma unroll
            for (int ni = 0; ni < 4; ++ni)
                acc[mi][ni] = __builtin_amdgcn_mfma_f32_16x16x32_bf16(af[mi], bf[ni], acc[mi][ni], 0, 0, 0);
        __syncthreads();
        cur ^= 1;
    }
    #pragma unroll
    for (int mi = 0; mi < 2; ++mi)
        #pragma unroll
        for (int ni = 0; ni < 4; ++ni)
            #pragma unroll
            for (int r = 0; r < 4; ++r)
                vk[((size_t)b * D_ + d0 + wr * 32 + mi * 16 + q * 4 + r) * D_ + e0 + wcn * 64 + ni * 16 + lr]
                    = f2b(acc[mi][ni][r] * (1.0f / 4096.0f));
}

// ---------------- kmean[b][d] = mean_n k[d][n] ----------------
__global__ __launch_bounds__(256) void k_kmean(const u16* __restrict__ kv, u16* __restrict__ kmean){
    int b = blockIdx.y, d = blockIdx.x, tid = threadIdx.x;
    const u16* p = kv + ((size_t)b * 1024 + d) * N_;
    float sum = 0.f;
    for (int i = tid * 8; i < N_; i += 2048){
        us8 v = *(const us8*)(p + i);
        #pragma unroll
        for (int j = 0; j < 8; ++j) sum += b2f(v[j]);
    }
    __shared__ float sm[4];
    for (int off = 32; off > 0; off >>= 1) sum += __shfl_down(sum, off);
    if ((tid & 63) == 0) sm[tid >> 6] = sum;
    __syncthreads();
    if (tid == 0) kmean[b * D_ + d] = f2b((sm[0] + sm[1] + sm[2] + sm[3]) * (1.0f / 4096.0f));
}

// ---------------- attn + RMS + gate -> og (B, N, D) ----------------
__global__ __launch_bounds__(256) void k_attn(const u16* __restrict__ qg, const u16* __restrict__ vk,
                                              const u16* __restrict__ kmean, const u16* __restrict__ anw,
                                              u16* __restrict__ og){
    __shared__ __attribute__((aligned(16))) u16 Xls[32][520];
    __shared__ float sred[4][32];
    int b = blockIdx.y, n0 = blockIdx.x * 32, tid = threadIdx.x;
    int wv = tid >> 6, l = tid & 63, lr = l & 15, q = l >> 4;
    const u16* qb = qg + ((size_t)b * N_ + n0) * 1024;
    #pragma unroll
    for (int it = 0; it < 8; ++it){
        int g = it * 256 + tid;
        int row = g >> 6, col = (g & 63) * 8;
        *(us8*)&Xls[row][col] = *(const us8*)(qb + (size_t)row * 1024 + col);
    }
    __syncthreads();
    const u16* vkb = vk + (size_t)b * D_ * D_ + (size_t)(wv * 128) * D_;
    const u16* kmb = kmean + (size_t)b * D_;
    f32x4 acc[8][2] = {};
    f32x4 accz[2] = {};
    for (int e0 = 0; e0 < 512; e0 += 32){
        frag8 bfv[2];
        #pragma unroll
        for (int nn = 0; nn < 2; ++nn)
            bfv[nn] = *(const frag8*)&Xls[nn * 16 + lr][e0 + q * 8];
        frag8 zf = {};
        if (lr == 0) zf = *(const frag8*)(kmb + e0 + q * 8);
        #pragma unroll
        for (int nn = 0; nn < 2; ++nn)
            accz[nn] = __builtin_amdgcn_mfma_f32_16x16x32_bf16(zf, bfv[nn], accz[nn], 0, 0, 0);
        #pragma unroll
        for (int dd = 0; dd < 8; ++dd){
            frag8 af = *(const frag8*)(vkb + (size_t)(dd * 16 + lr) * D_ + e0 + q * 8);
            #pragma unroll
            for (int nn = 0; nn < 2; ++nn)
                acc[dd][nn] = __builtin_amdgcn_mfma_f32_16x16x32_bf16(af, bfv[nn], acc[dd][nn], 0, 0, 0);
        }
    }
    float rz[2];
    #pragma unroll
    for (int nn = 0; nn < 2; ++nn)
        rz[nn] = 1.0f / (__shfl(accz[nn][0], lr) + 0.0005f);
    float ssq[2] = {0.f, 0.f};
    #pragma unroll
    for (int dd = 0; dd < 8; ++dd)
        #pragma unroll
        for (int nn = 0; nn < 2; ++nn)
            #pragma unroll
            for (int r = 0; r < 4; ++r){
                float a = acc[dd][nn][r] * rz[nn];
                acc[dd][nn][r] = a;
                ssq[nn] += a * a;
            }
    #pragma unroll
    for (int nn = 0; nn < 2; ++nn){
        ssq[nn] += __shfl_xor(ssq[nn], 16);
        ssq[nn] += __shfl_xor(ssq[nn], 32);
    }
    if (l < 16){ sred[wv][l] = ssq[0]; sred[wv][16 + l] = ssq[1]; }
    __syncthreads();
    float rinv[2];
    #pragma unroll
    for (int nn = 0; nn < 2; ++nn){
        float t = sred[0][nn * 16 + lr] + sred[1][nn * 16 + lr] + sred[2][nn * 16 + lr] + sred[3][nn * 16 + lr];
        rinv[nn] = rsqrtf(t * (1.0f / 512.0f) + 1e-6f);
    }
    #pragma unroll
    for (int dd = 0; dd < 8; ++dd){
        int dbase = wv * 128 + dd * 16 + q * 4;
        us4 aw4 = *(const us4*)(anw + dbase);
        #pragma unroll
        for (int nn = 0; nn < 2; ++nn){
            int n = n0 + nn * 16 + lr;
            us4 g4 = *(const us4*)(qb + (size_t)(nn * 16 + lr) * 1024 + 512 + dbase);
            us4 o4;
            #pragma unroll
            for (int r = 0; r < 4; ++r)
                o4[r] = f2b(acc[dd][nn][r] * rinv[nn] * b2f(aw4[r]) * b2f(g4[r]));
            *(us4*)(og + ((size_t)b * N_ + n) * D_ + dbase) = o4;
        }
    }
}

// ---------------- proj: po[b][c][n] = sum_d P[c][d] * og[b][n][d] — m97 + double-buffer ----------------
__global__ __launch_bounds__(256) void k_proj(const u16* __restrict__ P, const u16* __restrict__ og, float* __restrict__ po){
    __shared__ __attribute__((aligned(16))) u16 As[2][128 * 32];
    __shared__ __attribute__((aligned(16))) u16 Bs[2][128 * 32];
    int b = blockIdx.z, n0 = blockIdx.x * 128, c0 = blockIdx.y * 128;
    int tid = threadIdx.x, w = tid >> 6, l = tid & 63, lr = l & 15, q = l >> 4;
    int wr = w & 1, wcn = w >> 1;
    int srow = l >> 2, scol = (l & 3) * 8;
    const u16* ap = P + (size_t)(c0 + w * 16 + srow) * D_ + scol;
    const u16* bp = og + ((size_t)b * N_ + n0 + w * 16 + srow) * D_ + scol;
    f32x4 acc[4][4] = {};
    gl2l(ap, As[0] + w * 512);
    gl2l(ap + (size_t)64 * D_, As[0] + w * 512 + 2048);
    gl2l(bp, Bs[0] + w * 512);
    gl2l(bp + (size_t)64 * D_, Bs[0] + w * 512 + 2048);
    __syncthreads();
    int cur = 0;
    for (int t = 0; t < 16; ++t){
        if (t < 15){
            int kn = (t + 1) * 32;
            u16* la = As[cur ^ 1] + w * 512;
            u16* lb = Bs[cur ^ 1] + w * 512;
            gl2l(ap + kn, la);
            gl2l(ap + kn + (size_t)64 * D_, la + 2048);
            gl2l(bp + kn, lb);
            gl2l(bp + kn + (size_t)64 * D_, lb + 2048);
        }
        frag8 af[4], bf[4];
        #pragma unroll
        for (int i = 0; i < 4; ++i){
            af[i] = *(const frag8*)&As[cur][(wr * 64 + i * 16 + lr) * 32 + q * 8];
            bf[i] = *(const frag8*)&Bs[cur][(wcn * 64 + i * 16 + lr) * 32 + q * 8];
        }
        #pragma unroll
        for (int mi = 0; mi < 4; ++mi)
            #pragma unroll
            for (int ni = 0; ni < 4; ++ni)
                acc[mi][ni] = __builtin_amdgcn_mfma_f32_16x16x32_bf16(af[mi], bf[ni], acc[mi][ni], 0, 0, 0);
        __syncthreads();
        cur ^= 1;
    }
    #pragma unroll
    for (int mi = 0; mi < 4; ++mi){
        int cb = c0 + wr * 64 + mi * 16 + q * 4;
        #pragma unroll
        for (int ni = 0; ni < 4; ++ni){
            int n = n0 + wcn * 64 + ni * 16 + lr;
            #pragma unroll
            for (int r = 0; r < 4; ++r)
                po[((size_t)b * C_ + cb + r) * N_ + n] = acc[mi][ni][r];
        }
    }
}

// ---------------- BN2 stats (fp32 input) ----------------
__global__ __launch_bounds__(256) void k_bnstats(const float* __restrict__ y, const u16* __restrict__ gamma,
                                                 const u16* __restrict__ beta, float* __restrict__ s,
                                                 float* __restrict__ t){
    int ch = blockIdx.x, tid = threadIdx.x;
    float sum = 0.f, ss = 0.f;
    for (int b = 0; b < B_; ++b){
        const float* p = y + ((size_t)b * C_ + ch) * N_;
        for (int i = tid * 4; i < N_; i += 1024){
            f32x4 v = *(const f32x4*)(p + i);
            #pragma unroll
            for (int j = 0; j < 4; ++j){ sum += v[j]; ss += v[j] * v[j]; }
        }
    }
    __shared__ float sm[8];
    for (int off = 32; off > 0; off >>= 1){ sum += __shfl_down(sum, off); ss += __shfl_down(ss, off); }
    int w = tid >> 6;
    if ((tid & 63) == 0){ sm[w] = sum; sm[4 + w] = ss; }
    __syncthreads();
    if (tid == 0){
        float S = sm[0] + sm[1] + sm[2] + sm[3];
        float Q = sm[4] + sm[5] + sm[6] + sm[7];
        float mean = S / 32768.f;
        float var = Q / 32768.f - mean * mean;
        float inv = rsqrtf(var + 1e-5f);
        float sc = b2f(gamma[ch]) * inv;
        s[ch] = sc;
        t[ch] = b2f(beta[ch]) - mean * sc;
    }
}

// ---------------- apply BN2 in place (fp32) ----------------
__global__ __launch_bounds__(256) void k_bnapply(float* __restrict__ po, const float* __restrict__ s,
                                                 const float* __restrict__ t){
    size_t idx = ((size_t)blockIdx.x * 256 + threadIdx.x) * 8;
    int c = (int)((idx >> 12) & 511);
    float sc = s[c], tc = t[c];
    f32x4 a = *(const f32x4*)(po + idx);
    f32x4 b = *(const f32x4*)(po + idx + 4);
    #pragma unroll
    for (int j = 0; j < 4; ++j){ a[j] = a[j] * sc + tc; b[j] = b[j] * sc + tc; }
    *(f32x4*)(po + idx) = a;
    *(f32x4*)(po + idx + 4) = b;
}

extern "C" void kernel_launch(void* const* d_in, const int* in_sizes, int n_in,
                              void* d_out, int out_size, void* d_ws, size_t ws_size,
                              hipStream_t stream){
    float* out = (float*)d_out;
    char* ws = (char*)d_ws;

    // ---- workspace layout, 109 MB total ----
    int*   flag  = (int*)ws;
    float* s1    = (float*)(ws + 4096);
    float* t1    = (float*)(ws + 12288);
    float* s2    = (float*)(ws + 20480);
    float* t2    = (float*)(ws + 22528);
    float* mx    = (float*)(ws + 24576);
    u16*   kmean = (u16*)(ws + 28672);                 // 8*512 bf16
    u16*   g1c   = (u16*)(ws + 36864);
    u16*   b1c   = (u16*)(ws + 40960);
    u16*   anwc  = (u16*)(ws + 45056);
    u16*   g2c   = (u16*)(ws + 46080);
    u16*   b2c   = (u16*)(ws + 47104);
    u16*   wc    = (u16*)(ws + (1ull << 20));          // 2 MB
    u16*   pc    = (u16*)(ws + (3ull << 20));          // 0.5 MB
    u16*   Gb    = (u16*)(ws + (3584ull << 10));       // 0.5 MB
    float* T     = (float*)(ws + (4ull << 20));        // 4 MB
    u16*   vkall = (u16*)(ws + (8ull << 20));          // 4 MB
    u16*   kv    = (u16*)(ws + (12ull << 20));         // 64 MB -> ends 76 MB
    u16*   xc    = (u16*)(ws + (12ull << 20));         // 32 MB bf16 copy of x, shares kv (dead before gemm1)
    u16*   og    = (u16*)(ws + (76ull << 20));         // 32 MB -> ends 108 MB
    u16*   xT    = (u16*)(ws + (76ull << 20));         // 32 MB, shares og (xT dead before k_attn writes og)
    float* Gf    = (float*)(ws + (108ull << 20));      // 1 MB -> ends 109 MB

    // ---- detect + canonicalize params/weights to bf16 ----
    k_detect<<<1, 256, 0, stream>>>((const unsigned int*)d_in[0], flag);
    k_convert<<<512, 256, 0, stream>>>(d_in[1], wc, 1048576, flag);
    k_convert<<<1, 256, 0, stream>>>(d_in[2], g1c, 2048, flag);
    k_convert<<<1, 256, 0, stream>>>(d_in[3], b1c, 2048, flag);
    k_convert<<<1, 256, 0, stream>>>(d_in[4], anwc, 512, flag);
    k_convert<<<128, 256, 0, stream>>>(d_in[5], pc, 262144, flag);
    k_convert<<<1, 256, 0, stream>>>(d_in[6], g2c, 512, flag);
    k_convert<<<1, 256, 0, stream>>>(d_in[7], b2c, 512, flag);

    // ---- x canonical bf16 copy (into kv region, dead until gemm1) + transpose ----
    k_convert<<<8192, 256, 0, stream>>>(d_in[0], xc, 16777216, flag);
    k_xpose<<<dim3(64, 64), 256, 0, stream>>>(d_in[0], flag, xT);

    // ---- BN1 from sufficient statistics (split-K Gram, m97 from xc) ----
    hipMemsetAsync(Gf, 0, C_ * C_ * sizeof(float), stream);
    k_xmean<<<512, 256, 0, stream>>>(d_in[0], flag, mx);
    k_gram_split<<<dim3(4, 4, 32), 256, 0, stream>>>(xc, Gf);
    k_gram_fin<<<1024, 256, 0, stream>>>(Gf, Gb);
    k_wg<<<dim3(8, 32), 256, 0, stream>>>(wc, Gb, T);
    k_bn1fin<<<2048, 256, 0, stream>>>(T, wc, mx, g1c, b1c, s1, t1);

    // ---- phase 1: k(sigm), v ; vk + kmean ----
    k_gemm_act<1><<<dim3(32, 8, 8), 256, 0, stream>>>(wc, xT, s1, t1, kv);
    k_vk<<<dim3(4, 8, 8), 256, 0, stream>>>(kv, vkall);
    k_kmean<<<dim3(512, 8), 256, 0, stream>>>(kv, kmean);

    // ---- phase 2: q(sigm), g(silu) transposed ; attn ----
    k_gemm_act<2><<<dim3(32, 8, 8), 256, 0, stream>>>(wc, xT, s1, t1, kv);
    k_attn<<<dim3(128, 8), 256, 0, stream>>>(kv, vkall, kmean, anwc, og);

    // ---- proj (fp32 out into d_out) + BN2 in place ----
    k_proj<<<dim3(32, 4, 8), 256, 0, stream>>>(pc, og, out);
    k_bnstats<<<512, 256, 0, stream>>>(out, g2c, b2c, s2, t2);
    k_bnapply<<<8192, 256, 0, stream>>>(out, s2, t2);
}

// Round 8
// 563.275 us; speedup vs baseline: 1.1818x; 1.1818x over previous
//
#include <hip/hip_runtime.h>
#include <hip/hip_bf16.h>
#include <math.h>

typedef unsigned short u16;
typedef __attribute__((ext_vector_type(8))) short frag8;
typedef __attribute__((ext_vector_type(4))) float f32x4;
typedef __attribute__((ext_vector_type(8))) unsigned short us8;
typedef __attribute__((ext_vector_type(4))) unsigned short us4;

#define B_ 8
#define C_ 512
#define D_ 512
#define N_ 4096

__device__ __forceinline__ float b2f(u16 u){ union { unsigned int i; float f; } v; v.i = ((unsigned int)u) << 16; return v.f; }
__device__ __forceinline__ u16 f2b(float f){ union { float f; unsigned int i; } v; v.f = f; unsigned int x = v.i; return (u16)((x + 0x7fffu + ((x >> 16) & 1u)) >> 16); }
__device__ __forceinline__ float sigm(float x){ return 1.0f / (1.0f + __expf(-x)); }

// async global->LDS, 16B per lane; LDS dest is wave-uniform base + lane*16
__device__ __forceinline__ void gl2l(const u16* g, u16* l){
    __builtin_amdgcn_global_load_lds((const __attribute__((address_space(1))) void*)g,
                                     (__attribute__((address_space(3))) void*)l, 16, 0, 0);
}

// load 8 consecutive elements as bf16 from fp32 (fl=1) or bf16 (fl=0) source
__device__ __forceinline__ us8 load_x8(const void* __restrict__ x, int fl, size_t off){
    if (fl){
        const float* p = (const float*)x + off;
        f32x4 a = *(const f32x4*)p;
        f32x4 b = *(const f32x4*)(p + 4);
        us8 o;
        #pragma unroll
        for (int j = 0; j < 4; ++j){ o[j] = f2b(a[j]); o[4 + j] = f2b(b[j]); }
        return o;
    }
    return *(const us8*)((const u16*)x + off);
}

// ---------------- dtype detect: bf16 vs fp32 ----------------
__global__ __launch_bounds__(256) void k_detect(const unsigned int* __restrict__ x, int* __restrict__ flag){
    int tid = threadIdx.x;
    unsigned int w = x[tid];
    int e = (int)((w >> 7) & 0xFFu);
    int in = (e >= 100 && e <= 140) ? 1 : 0;
    __shared__ int sm[4];
    for (int off = 32; off > 0; off >>= 1) in += __shfl_down(in, off);
    if ((tid & 63) == 0) sm[tid >> 6] = in;
    __syncthreads();
    if (tid == 0) *flag = ((sm[0] + sm[1] + sm[2] + sm[3]) < 128) ? 1 : 0;  // 1 = fp32
}

__global__ __launch_bounds__(256) void k_convert(const void* __restrict__ src, u16* __restrict__ dst,
                                                 int n, const int* __restrict__ flag){
    int i = (blockIdx.x * 256 + threadIdx.x) * 8;
    if (i >= n) return;
    *(us8*)(dst + i) = load_x8(src, *flag, (size_t)i);
}

// ---------------- fused prep: one pass over x -> xc (bf16, b,C,N), xT (bf16, b,N,C), mx (mean) ----------------
// 64x64 tiles; row sums reduced in 4-lane groups, atomicAdd scaled partials into mx.
__global__ __launch_bounds__(256) void k_prep(const void* __restrict__ x, const int* __restrict__ flag,
                                              u16* __restrict__ xc, u16* __restrict__ xT, float* __restrict__ mx){
    __shared__ __attribute__((aligned(16))) u16 T[64][72];
    int rt = blockIdx.y;              // row tile over b*C
    int b = rt >> 3, c0 = (rt & 7) * 64;
    int n0 = blockIdx.x * 64;
    int tid = threadIdx.x, fl = *flag;
    int row = tid >> 2, cg = (tid & 3) * 16;
    size_t base = ((size_t)b * C_ + c0 + row) * N_ + n0 + cg;
    us8 v0 = load_x8(x, fl, base);
    us8 v1 = load_x8(x, fl, base + 8);
    // bf16 canonical copy (same layout as x)
    u16* xcd = xc + base;
    *(us8*)xcd = v0;
    *(us8*)(xcd + 8) = v1;
    // row partial sum (16 elems) -> reduce over the 4 lanes sharing this row -> atomic
    float s = 0.f;
    #pragma unroll
    for (int j = 0; j < 8; ++j) s += b2f(v0[j]) + b2f(v1[j]);
    s += __shfl_xor(s, 1);
    s += __shfl_xor(s, 2);
    if ((tid & 3) == 0) atomicAdd(&mx[c0 + row], s * (1.0f / 32768.0f));
    // transpose via LDS
    #pragma unroll
    for (int j = 0; j < 8; ++j){ T[cg + j][row] = v0[j]; T[cg + 8 + j][row] = v1[j]; }
    __syncthreads();
    int col = tid >> 2, rg = (tid & 3) * 16;
    us8 o0 = *(const us8*)&T[col][rg];
    us8 o1 = *(const us8*)&T[col][rg + 8];
    u16* dst = xT + ((size_t)b * N_ + n0 + col) * C_ + c0 + rg;
    *(us8*)dst = o0;
    *(us8*)(dst + 8) = o1;
}

// ---------------- Gram split-K (m97): Gf[k][k'] += partial over (b, n-chunk), from bf16 xc ----------------
// 128x128 tile, BK=32, gl2l staging, 2x2 wave quadrants (64x64 each).
// grid (4 kp-tiles, 4 k-tiles, 32 splits): split s -> b = s>>2, n-chunk = (s&3)*1024
__global__ __launch_bounds__(256) void k_gram_split(const u16* __restrict__ xc, float* __restrict__ Gf){
    __shared__ __attribute__((aligned(16))) u16 As[128 * 32];
    __shared__ __attribute__((aligned(16))) u16 Bs[128 * 32];
    int k0 = blockIdx.y * 128, kp0 = blockIdx.x * 128;
    int s = blockIdx.z;
    int b = s >> 2, nbase = (s & 3) * 1024;
    int tid = threadIdx.x, w = tid >> 6, l = tid & 63, lr = l & 15, q = l >> 4;
    int wr = w & 1, wcn = w >> 1;
    int srow = l >> 2, scol = (l & 3) * 8;
    const u16* ap = xc + ((size_t)b * C_ + k0 + w * 16 + srow) * N_ + nbase + scol;
    const u16* bp = xc + ((size_t)b * C_ + kp0 + w * 16 + srow) * N_ + nbase + scol;
    u16* la = As + w * 512;
    u16* lb = Bs + w * 512;
    f32x4 acc[4][4] = {};
    for (int n0 = 0; n0 < 1024; n0 += 32){
        gl2l(ap + n0, la);
        gl2l(ap + n0 + (size_t)64 * N_, la + 2048);
        gl2l(bp + n0, lb);
        gl2l(bp + n0 + (size_t)64 * N_, lb + 2048);
        __syncthreads();
        frag8 af[4], bf[4];
        #pragma unroll
        for (int i = 0; i < 4; ++i){
            af[i] = *(const frag8*)&As[(wr * 64 + i * 16 + lr) * 32 + q * 8];
            bf[i] = *(const frag8*)&Bs[(wcn * 64 + i * 16 + lr) * 32 + q * 8];
        }
        #pragma unroll
        for (int mi = 0; mi < 4; ++mi)
            #pragma unroll
            for (int ni = 0; ni < 4; ++ni)
                acc[mi][ni] = __builtin_amdgcn_mfma_f32_16x16x32_bf16(af[mi], bf[ni], acc[mi][ni], 0, 0, 0);
        __syncthreads();
    }
    #pragma unroll
    for (int mi = 0; mi < 4; ++mi)
        #pragma unroll
        for (int ni = 0; ni < 4; ++ni)
            #pragma unroll
            for (int r = 0; r < 4; ++r)
                atomicAdd(&Gf[(size_t)(k0 + wr * 64 + mi * 16 + q * 4 + r) * C_ + kp0 + wcn * 64 + ni * 16 + lr],
                          acc[mi][ni][r]);
}

// Gf fp32 -> Gb bf16 with 1/32768 scale
__global__ __launch_bounds__(256) void k_gram_fin(const float* __restrict__ Gf, u16* __restrict__ Gb){
    int i = blockIdx.x * 256 + threadIdx.x;
    Gb[i] = f2b(Gf[i] * (1.0f / 32768.0f));
}

// ---------------- T = W * G (fp32 out), G symmetric ----------------
__global__ __launch_bounds__(256) void k_wg(const u16* __restrict__ wc, const u16* __restrict__ Gb, float* __restrict__ T){
    __shared__ __attribute__((aligned(16))) u16 As[64][40];
    __shared__ __attribute__((aligned(16))) u16 Bs[64][40];
    int o0 = blockIdx.y * 64, kp0 = blockIdx.x * 64;
    int tid = threadIdx.x, row = tid >> 2, cg = (tid & 3) * 8;
    const u16* ap = wc + (size_t)(o0 + row) * C_ + cg;
    const u16* bp = Gb + (size_t)(kp0 + row) * C_ + cg;
    int w = tid >> 6, l = tid & 63, lr = l & 15, q = l >> 4;
    f32x4 acc[4] = {};
    for (int k0 = 0; k0 < 512; k0 += 32){
        *(us8*)&As[row][cg] = *(const us8*)(ap + k0);
        *(us8*)&Bs[row][cg] = *(const us8*)(bp + k0);
        __syncthreads();
        frag8 af = *(const frag8*)&As[w * 16 + lr][q * 8];
        #pragma unroll
        for (int t4 = 0; t4 < 4; ++t4){
            frag8 bfv = *(const frag8*)&Bs[t4 * 16 + lr][q * 8];
            acc[t4] = __builtin_amdgcn_mfma_f32_16x16x32_bf16(af, bfv, acc[t4], 0, 0, 0);
        }
        __syncthreads();
    }
    #pragma unroll
    for (int t4 = 0; t4 < 4; ++t4)
        #pragma unroll
        for (int r = 0; r < 4; ++r)
            T[(size_t)(o0 + w * 16 + q * 4 + r) * C_ + kp0 + t4 * 16 + lr] = acc[t4][r];
}

// ---------------- BN1 finalize ----------------
__global__ __launch_bounds__(256) void k_bn1fin(const float* __restrict__ T, const u16* __restrict__ wc,
                                                const float* __restrict__ mx, const u16* __restrict__ g1,
                                                const u16* __restrict__ b1, float* __restrict__ s1,
                                                float* __restrict__ t1){
    int o = blockIdx.x, tid = threadIdx.x;
    float e2 = 0.f, mn = 0.f;
    for (int k = tid; k < 512; k += 256){
        float wv = b2f(wc[(size_t)o * C_ + k]);
        e2 += T[(size_t)o * C_ + k] * wv;
        mn += wv * mx[k];
    }
    __shared__ float sm[8];
    for (int off = 32; off > 0; off >>= 1){ e2 += __shfl_down(e2, off); mn += __shfl_down(mn, off); }
    int w = tid >> 6;
    if ((tid & 63) == 0){ sm[w] = e2; sm[4 + w] = mn; }
    __syncthreads();
    if (tid == 0){
        float E2 = sm[0] + sm[1] + sm[2] + sm[3];
        float M  = sm[4] + sm[5] + sm[6] + sm[7];
        float var = E2 - M * M;
        float inv = rsqrtf(var + 1e-5f);
        float sc = b2f(g1[o]) * inv;
        s1[o] = sc;
        t1[o] = b2f(b1[o]) - M * sc;
    }
}

// ---------------- GEMM1 (batched), fused BN + activation — m97 structure ----------------
template<int PHASE>
__global__ __launch_bounds__(256) void k_gemm_act(const u16* __restrict__ wc, const u16* __restrict__ xT,
                                                  const float* __restrict__ s1, const float* __restrict__ t1,
                                                  u16* __restrict__ dst){
    __shared__ __attribute__((aligned(16))) u16 As[128 * 32];
    __shared__ __attribute__((aligned(16))) u16 Bs[128 * 32];
    int b = blockIdx.z, n0 = blockIdx.x * 128, my = blockIdx.y;
    int c0 = (PHASE == 1) ? (512 + my * 128) : ((my < 4) ? my * 128 : 1536 + (my - 4) * 128);
    int tid = threadIdx.x, w = tid >> 6, l = tid & 63, lr = l & 15, q = l >> 4;
    int wr = w & 1, wcn = w >> 1;              // wave quadrant: rows wr*64, cols wcn*64
    int srow = l >> 2, scol = (l & 3) * 8;     // staging lane map (16 rows x 32 cols per wave-chunk)
    const u16* ap = wc + (size_t)(c0 + w * 16 + srow) * C_ + scol;
    const u16* bp = xT + ((size_t)b * N_ + n0 + w * 16 + srow) * C_ + scol;
    u16* la = As + w * 512;
    u16* lb = Bs + w * 512;
    f32x4 acc[4][4] = {};
    for (int k0 = 0; k0 < 512; k0 += 32){
        gl2l(ap + k0, la);
        gl2l(ap + k0 + (size_t)64 * C_, la + 2048);
        gl2l(bp + k0, lb);
        gl2l(bp + k0 + (size_t)64 * C_, lb + 2048);
        __syncthreads();
        frag8 af[4], bf[4];
        #pragma unroll
        for (int i = 0; i < 4; ++i){
            af[i] = *(const frag8*)&As[(wr * 64 + i * 16 + lr) * 32 + q * 8];
            bf[i] = *(const frag8*)&Bs[(wcn * 64 + i * 16 + lr) * 32 + q * 8];
        }
        #pragma unroll
        for (int mi = 0; mi < 4; ++mi)
            #pragma unroll
            for (int ni = 0; ni < 4; ++ni)
                acc[mi][ni] = __builtin_amdgcn_mfma_f32_16x16x32_bf16(af[mi], bf[ni], acc[mi][ni], 0, 0, 0);
        __syncthreads();
    }
    #pragma unroll
    for (int mi = 0; mi < 4; ++mi){
        int cb = c0 + wr * 64 + mi * 16 + q * 4;
        #pragma unroll
        for (int ni = 0; ni < 4; ++ni){
            int n = n0 + wcn * 64 + ni * 16 + lr;
            us4 o4;
            #pragma unroll
            for (int r = 0; r < 4; ++r){
                int c = cb + r;
                float ybn = acc[mi][ni][r] * s1[c] + t1[c];
                float ov = (c < 1024) ? sigm(ybn) : ((c < 1536) ? ybn : ybn * sigm(ybn));
                if (PHASE == 1)
                    dst[((size_t)b * 1024 + (c - 512)) * N_ + n] = f2b(ov);
                else
                    o4[r] = f2b(ov);
            }
            if (PHASE == 2){
                int col = (cb < 512) ? cb : (cb - 1024);
                *(us4*)(dst + ((size_t)b * N_ + n) * 1024 + col) = o4;
            }
        }
    }
}

// ---------------- vk[b][d][e] = (1/N) sum_n v[d][n] * k[e][n] — m97 structure ----------------
// 64d x 128e tile, BK=32, gl2l staging, 2x2 wave quadrants (32x64 each), grid (4,8,8).
__global__ __launch_bounds__(256) void k_vk(const u16* __restrict__ kv, u16* __restrict__ vk){
    __shared__ __attribute__((aligned(16))) u16 As[64 * 32];    // v-tile
    __shared__ __attribute__((aligned(16))) u16 Bs[128 * 32];   // k-tile
    int b = blockIdx.z, d0 = blockIdx.y * 64, e0 = blockIdx.x * 128;
    int tid = threadIdx.x, w = tid >> 6, l = tid & 63, lr = l & 15, q = l >> 4;
    int wr = w & 1, wcn = w >> 1;               // quadrant: d rows wr*32, e cols wcn*64
    int srow = l >> 2, scol = (l & 3) * 8;
    const u16* ap = kv + ((size_t)b * 1024 + 512 + d0 + w * 16 + srow) * N_ + scol;
    const u16* bp = kv + ((size_t)b * 1024 + e0 + w * 32 + srow) * N_ + scol;
    u16* la = As + w * 512;      // 16 rows x 32
    u16* lb = Bs + w * 1024;     // 32 rows x 32
    f32x4 acc[2][4] = {};
    for (int n0 = 0; n0 < N_; n0 += 32){
        gl2l(ap + n0, la);
        gl2l(bp + n0, lb);
        gl2l(bp + n0 + (size_t)16 * N_, lb + 512);
        __syncthreads();
        frag8 af[2], bf[4];
        #pragma unroll
        for (int i = 0; i < 2; ++i)
            af[i] = *(const frag8*)&As[(wr * 32 + i * 16 + lr) * 32 + q * 8];
        #pragma unroll
        for (int i = 0; i < 4; ++i)
            bf[i] = *(const frag8*)&Bs[(wcn * 64 + i * 16 + lr) * 32 + q * 8];
        #pragma unroll
        for (int mi = 0; mi < 2; ++mi)
            #pragma unroll
            for (int ni = 0; ni < 4; ++ni)
                acc[mi][ni] = __builtin_amdgcn_mfma_f32_16x16x32_bf16(af[mi], bf[ni], acc[mi][ni], 0, 0, 0);
        __syncthreads();
    }
    #pragma unroll
    for (int mi = 0; mi < 2; ++mi)
        #pragma unroll
        for (int ni = 0; ni < 4; ++ni)
            #pragma unroll
            for (int r = 0; r < 4; ++r)
                vk[((size_t)b * D_ + d0 + wr * 32 + mi * 16 + q * 4 + r) * D_ + e0 + wcn * 64 + ni * 16 + lr]
                    = f2b(acc[mi][ni][r] * (1.0f / 4096.0f));
}

// ---------------- kmean[b][d] = mean_n k[d][n] ----------------
__global__ __launch_bounds__(256) void k_kmean(const u16* __restrict__ kv, u16* __restrict__ kmean){
    int b = blockIdx.y, d = blockIdx.x, tid = threadIdx.x;
    const u16* p = kv + ((size_t)b * 1024 + d) * N_;
    float sum = 0.f;
    for (int i = tid * 8; i < N_; i += 2048){
        us8 v = *(const us8*)(p + i);
        #pragma unroll
        for (int j = 0; j < 8; ++j) sum += b2f(v[j]);
    }
    __shared__ float sm[4];
    for (int off = 32; off > 0; off >>= 1) sum += __shfl_down(sum, off);
    if ((tid & 63) == 0) sm[tid >> 6] = sum;
    __syncthreads();
    if (tid == 0) kmean[b * D_ + d] = f2b((sm[0] + sm[1] + sm[2] + sm[3]) * (1.0f / 4096.0f));
}

// ---------------- attn + RMS + gate -> og (B, N, D) ----------------
__global__ __launch_bounds__(256) void k_attn(const u16* __restrict__ qg, const u16* __restrict__ vk,
                                              const u16* __restrict__ kmean, const u16* __restrict__ anw,
                                              u16* __restrict__ og){
    __shared__ __attribute__((aligned(16))) u16 Xls[32][520];
    __shared__ float sred[4][32];
    int b = blockIdx.y, n0 = blockIdx.x * 32, tid = threadIdx.x;
    int wv = tid >> 6, l = tid & 63, lr = l & 15, q = l >> 4;
    const u16* qb = qg + ((size_t)b * N_ + n0) * 1024;
    #pragma unroll
    for (int it = 0; it < 8; ++it){
        int g = it * 256 + tid;
        int row = g >> 6, col = (g & 63) * 8;
        *(us8*)&Xls[row][col] = *(const us8*)(qb + (size_t)row * 1024 + col);
    }
    __syncthreads();
    const u16* vkb = vk + (size_t)b * D_ * D_ + (size_t)(wv * 128) * D_;
    const u16* kmb = kmean + (size_t)b * D_;
    f32x4 acc[8][2] = {};
    f32x4 accz[2] = {};
    for (int e0 = 0; e0 < 512; e0 += 32){
        frag8 bfv[2];
        #pragma unroll
        for (int nn = 0; nn < 2; ++nn)
            bfv[nn] = *(const frag8*)&Xls[nn * 16 + lr][e0 + q * 8];
        frag8 zf = {};
        if (lr == 0) zf = *(const frag8*)(kmb + e0 + q * 8);
        #pragma unroll
        for (int nn = 0; nn < 2; ++nn)
            accz[nn] = __builtin_amdgcn_mfma_f32_16x16x32_bf16(zf, bfv[nn], accz[nn], 0, 0, 0);
        #pragma unroll
        for (int dd = 0; dd < 8; ++dd){
            frag8 af = *(const frag8*)(vkb + (size_t)(dd * 16 + lr) * D_ + e0 + q * 8);
            #pragma unroll
            for (int nn = 0; nn < 2; ++nn)
                acc[dd][nn] = __builtin_amdgcn_mfma_f32_16x16x32_bf16(af, bfv[nn], acc[dd][nn], 0, 0, 0);
        }
    }
    float rz[2];
    #pragma unroll
    for (int nn = 0; nn < 2; ++nn)
        rz[nn] = 1.0f / (__shfl(accz[nn][0], lr) + 0.0005f);
    float ssq[2] = {0.f, 0.f};
    #pragma unroll
    for (int dd = 0; dd < 8; ++dd)
        #pragma unroll
        for (int nn = 0; nn < 2; ++nn)
            #pragma unroll
            for (int r = 0; r < 4; ++r){
                float a = acc[dd][nn][r] * rz[nn];
                acc[dd][nn][r] = a;
                ssq[nn] += a * a;
            }
    #pragma unroll
    for (int nn = 0; nn < 2; ++nn){
        ssq[nn] += __shfl_xor(ssq[nn], 16);
        ssq[nn] += __shfl_xor(ssq[nn], 32);
    }
    if (l < 16){ sred[wv][l] = ssq[0]; sred[wv][16 + l] = ssq[1]; }
    __syncthreads();
    float rinv[2];
    #pragma unroll
    for (int nn = 0; nn < 2; ++nn){
        float t = sred[0][nn * 16 + lr] + sred[1][nn * 16 + lr] + sred[2][nn * 16 + lr] + sred[3][nn * 16 + lr];
        rinv[nn] = rsqrtf(t * (1.0f / 512.0f) + 1e-6f);
    }
    #pragma unroll
    for (int dd = 0; dd < 8; ++dd){
        int dbase = wv * 128 + dd * 16 + q * 4;
        us4 aw4 = *(const us4*)(anw + dbase);
        #pragma unroll
        for (int nn = 0; nn < 2; ++nn){
            int n = n0 + nn * 16 + lr;
            us4 g4 = *(const us4*)(qb + (size_t)(nn * 16 + lr) * 1024 + 512 + dbase);
            us4 o4;
            #pragma unroll
            for (int r = 0; r < 4; ++r)
                o4[r] = f2b(acc[dd][nn][r] * rinv[nn] * b2f(aw4[r]) * b2f(g4[r]));
            *(us4*)(og + ((size_t)b * N_ + n) * D_ + dbase) = o4;
        }
    }
}

// ---------------- proj: po[b][c][n] = sum_d P[c][d] * og[b][n][d] — m97 structure ----------------
__global__ __launch_bounds__(256) void k_proj(const u16* __restrict__ P, const u16* __restrict__ og, float* __restrict__ po){
    __shared__ __attribute__((aligned(16))) u16 As[128 * 32];
    __shared__ __attribute__((aligned(16))) u16 Bs[128 * 32];
    int b = blockIdx.z, n0 = blockIdx.x * 128, c0 = blockIdx.y * 128;
    int tid = threadIdx.x, w = tid >> 6, l = tid & 63, lr = l & 15, q = l >> 4;
    int wr = w & 1, wcn = w >> 1;
    int srow = l >> 2, scol = (l & 3) * 8;
    const u16* ap = P + (size_t)(c0 + w * 16 + srow) * D_ + scol;
    const u16* bp = og + ((size_t)b * N_ + n0 + w * 16 + srow) * D_ + scol;
    u16* la = As + w * 512;
    u16* lb = Bs + w * 512;
    f32x4 acc[4][4] = {};
    for (int k0 = 0; k0 < 512; k0 += 32){
        gl2l(ap + k0, la);
        gl2l(ap + k0 + (size_t)64 * D_, la + 2048);
        gl2l(bp + k0, lb);
        gl2l(bp + k0 + (size_t)64 * D_, lb + 2048);
        __syncthreads();
        frag8 af[4], bf[4];
        #pragma unroll
        for (int i = 0; i < 4; ++i){
            af[i] = *(const frag8*)&As[(wr * 64 + i * 16 + lr) * 32 + q * 8];
            bf[i] = *(const frag8*)&Bs[(wcn * 64 + i * 16 + lr) * 32 + q * 8];
        }
        #pragma unroll
        for (int mi = 0; mi < 4; ++mi)
            #pragma unroll
            for (int ni = 0; ni < 4; ++ni)
                acc[mi][ni] = __builtin_amdgcn_mfma_f32_16x16x32_bf16(af[mi], bf[ni], acc[mi][ni], 0, 0, 0);
        __syncthreads();
    }
    #pragma unroll
    for (int mi = 0; mi < 4; ++mi){
        int cb = c0 + wr * 64 + mi * 16 + q * 4;
        #pragma unroll
        for (int ni = 0; ni < 4; ++ni){
            int n = n0 + wcn * 64 + ni * 16 + lr;
            #pragma unroll
            for (int r = 0; r < 4; ++r)
                po[((size_t)b * C_ + cb + r) * N_ + n] = acc[mi][ni][r];
        }
    }
}

// ---------------- BN2 stats (fp32 input) ----------------
__global__ __launch_bounds__(256) void k_bnstats(const float* __restrict__ y, const u16* __restrict__ gamma,
                                                 const u16* __restrict__ beta, float* __restrict__ s,
                                                 float* __restrict__ t){
    int ch = blockIdx.x, tid = threadIdx.x;
    float sum = 0.f, ss = 0.f;
    for (int b = 0; b < B_; ++b){
        const float* p = y + ((size_t)b * C_ + ch) * N_;
        for (int i = tid * 4; i < N_; i += 1024){
            f32x4 v = *(const f32x4*)(p + i);
            #pragma unroll
            for (int j = 0; j < 4; ++j){ sum += v[j]; ss += v[j] * v[j]; }
        }
    }
    __shared__ float sm[8];
    for (int off = 32; off > 0; off >>= 1){ sum += __shfl_down(sum, off); ss += __shfl_down(ss, off); }
    int w = tid >> 6;
    if ((tid & 63) == 0){ sm[w] = sum; sm[4 + w] = ss; }
    __syncthreads();
    if (tid == 0){
        float S = sm[0] + sm[1] + sm[2] + sm[3];
        float Q = sm[4] + sm[5] + sm[6] + sm[7];
        float mean = S / 32768.f;
        float var = Q / 32768.f - mean * mean;
        float inv = rsqrtf(var + 1e-5f);
        float sc = b2f(gamma[ch]) * inv;
        s[ch] = sc;
        t[ch] = b2f(beta[ch]) - mean * sc;
    }
}

// ---------------- apply BN2 in place (fp32) ----------------
__global__ __launch_bounds__(256) void k_bnapply(float* __restrict__ po, const float* __restrict__ s,
                                                 const float* __restrict__ t){
    size_t idx = ((size_t)blockIdx.x * 256 + threadIdx.x) * 8;
    int c = (int)((idx >> 12) & 511);
    float sc = s[c], tc = t[c];
    f32x4 a = *(const f32x4*)(po + idx);
    f32x4 b = *(const f32x4*)(po + idx + 4);
    #pragma unroll
    for (int j = 0; j < 4; ++j){ a[j] = a[j] * sc + tc; b[j] = b[j] * sc + tc; }
    *(f32x4*)(po + idx) = a;
    *(f32x4*)(po + idx + 4) = b;
}

extern "C" void kernel_launch(void* const* d_in, const int* in_sizes, int n_in,
                              void* d_out, int out_size, void* d_ws, size_t ws_size,
                              hipStream_t stream){
    float* out = (float*)d_out;
    char* ws = (char*)d_ws;

    // ---- workspace layout, 109 MB total ----
    int*   flag  = (int*)ws;
    float* s1    = (float*)(ws + 4096);
    float* t1    = (float*)(ws + 12288);
    float* s2    = (float*)(ws + 20480);
    float* t2    = (float*)(ws + 22528);
    float* mx    = (float*)(ws + 24576);
    u16*   kmean = (u16*)(ws + 28672);                 // 8*512 bf16
    u16*   g1c   = (u16*)(ws + 36864);
    u16*   b1c   = (u16*)(ws + 40960);
    u16*   anwc  = (u16*)(ws + 45056);
    u16*   g2c   = (u16*)(ws + 46080);
    u16*   b2c   = (u16*)(ws + 47104);
    u16*   wc    = (u16*)(ws + (1ull << 20));          // 2 MB
    u16*   pc    = (u16*)(ws + (3ull << 20));          // 0.5 MB
    u16*   Gb    = (u16*)(ws + (3584ull << 10));       // 0.5 MB
    float* T     = (float*)(ws + (4ull << 20));        // 4 MB
    u16*   vkall = (u16*)(ws + (8ull << 20));          // 4 MB
    u16*   kv    = (u16*)(ws + (12ull << 20));         // 64 MB -> ends 76 MB
    u16*   xc    = (u16*)(ws + (12ull << 20));         // 32 MB bf16 copy of x, shares kv (dead before gemm1)
    u16*   og    = (u16*)(ws + (76ull << 20));         // 32 MB -> ends 108 MB
    u16*   xT    = (u16*)(ws + (76ull << 20));         // 32 MB, shares og (xT dead before k_attn writes og)
    float* Gf    = (float*)(ws + (108ull << 20));      // 1 MB -> ends 109 MB

    // ---- detect + canonicalize params/weights to bf16 ----
    k_detect<<<1, 256, 0, stream>>>((const unsigned int*)d_in[0], flag);
    k_convert<<<512, 256, 0, stream>>>(d_in[1], wc, 1048576, flag);
    k_convert<<<1, 256, 0, stream>>>(d_in[2], g1c, 2048, flag);
    k_convert<<<1, 256, 0, stream>>>(d_in[3], b1c, 2048, flag);
    k_convert<<<1, 256, 0, stream>>>(d_in[4], anwc, 512, flag);
    k_convert<<<128, 256, 0, stream>>>(d_in[5], pc, 262144, flag);
    k_convert<<<1, 256, 0, stream>>>(d_in[6], g2c, 512, flag);
    k_convert<<<1, 256, 0, stream>>>(d_in[7], b2c, 512, flag);

    // ---- fused single pass over x: xc (bf16), xT (bf16 transposed), mx (channel means) ----
    hipMemsetAsync(mx, 0, C_ * sizeof(float), stream);
    hipMemsetAsync(Gf, 0, C_ * C_ * sizeof(float), stream);
    k_prep<<<dim3(64, 64), 256, 0, stream>>>(d_in[0], flag, xc, xT, mx);

    // ---- BN1 from sufficient statistics (split-K Gram, m97 from xc) ----
    k_gram_split<<<dim3(4, 4, 32), 256, 0, stream>>>(xc, Gf);
    k_gram_fin<<<1024, 256, 0, stream>>>(Gf, Gb);
    k_wg<<<dim3(8, 32), 256, 0, stream>>>(wc, Gb, T);
    k_bn1fin<<<2048, 256, 0, stream>>>(T, wc, mx, g1c, b1c, s1, t1);

    // ---- phase 1: k(sigm), v ; vk + kmean ----
    k_gemm_act<1><<<dim3(32, 8, 8), 256, 0, stream>>>(wc, xT, s1, t1, kv);
    k_vk<<<dim3(4, 8, 8), 256, 0, stream>>>(kv, vkall);
    k_kmean<<<dim3(512, 8), 256, 0, stream>>>(kv, kmean);

    // ---- phase 2: q(sigm), g(silu) transposed ; attn ----
    k_gemm_act<2><<<dim3(32, 8, 8), 256, 0, stream>>>(wc, xT, s1, t1, kv);
    k_attn<<<dim3(128, 8), 256, 0, stream>>>(kv, vkall, kmean, anwc, og);

    // ---- proj (fp32 out into d_out) + BN2 in place ----
    k_proj<<<dim3(32, 4, 8), 256, 0, stream>>>(pc, og, out);
    k_bnstats<<<512, 256, 0, stream>>>(out, g2c, b2c, s2, t2);
    k_bnapply<<<8192, 256, 0, stream>>>(out, s2, t2);
}